// Round 6
// baseline (456.428 us; speedup 1.0000x reference)
//
#include <hip/hip_runtime.h>

typedef __bf16 bf16x8 __attribute__((ext_vector_type(8)));
typedef __bf16 bf16x4 __attribute__((ext_vector_type(4)));
typedef float  f32x4  __attribute__((ext_vector_type(4)));

#define NW 8       // waves per block (512 threads)
#define HPAD 68    // bf16 elems per LDS h-row (136 B); measured 0 bank conflicts
#define NFRAG 36   // 12 (W1) + 20 (W2) + 4 (W3) fragment tiles
#define LDS_WAIT() asm volatile("s_waitcnt lgkmcnt(0)" ::: "memory")

static __device__ __forceinline__ bf16x8 ld_frag_lds8(const __bf16* p) {
    bf16x4 lo = *(const bf16x4*)p;
    bf16x4 hi = *(const bf16x4*)(p + 4);
    bf16x8 r;
    r[0] = lo[0]; r[1] = lo[1]; r[2] = lo[2]; r[3] = lo[3];
    r[4] = hi[0]; r[5] = hi[1]; r[6] = hi[2]; r[7] = hi[3];
    return r;
}

static __device__ __forceinline__ bf16x8 cvt_frag(float4 v0, float4 v1) {
    bf16x8 r;
    r[0] = (__bf16)v0.x; r[1] = (__bf16)v0.y; r[2] = (__bf16)v0.z; r[3] = (__bf16)v0.w;
    r[4] = (__bf16)v1.x; r[5] = (__bf16)v1.y; r[6] = (__bf16)v1.z; r[7] = (__bf16)v1.w;
    return r;
}

// ReLU(acc + b) -> LayerNorm(*g, +be) -> bf16 scatter into per-wave LDS tile (C-layout).
static __device__ __forceinline__ void ln_epilogue(const f32x4* acc, const float* bv,
                                                   const float* gv, const float* ev,
                                                   __bf16* hp, int n16, int q) {
    float u[4][4];
    float sm[4] = {0.f, 0.f, 0.f, 0.f};
    float sq[4] = {0.f, 0.f, 0.f, 0.f};
#pragma unroll
    for (int t = 0; t < 4; ++t)
#pragma unroll
        for (int j = 0; j < 4; ++j) {
            float x = acc[t][j] + bv[t];
            x = fmaxf(x, 0.0f);
            u[t][j] = x;
            sm[j] += x;
            sq[j] += x * x;
        }
#pragma unroll
    for (int msk = 1; msk <= 8; msk <<= 1)
#pragma unroll
        for (int j = 0; j < 4; ++j) {
            sm[j] += __shfl_xor(sm[j], msk, 64);
            sq[j] += __shfl_xor(sq[j], msk, 64);
        }
    float mean[4], rstd[4];
#pragma unroll
    for (int j = 0; j < 4; ++j) {
        mean[j] = sm[j] * 0.015625f;
        float v = sq[j] * 0.015625f - mean[j] * mean[j];
        rstd[j] = rsqrtf(fmaxf(v, 0.0f) + 1e-5f);
    }
#pragma unroll
    for (int t = 0; t < 4; ++t)
#pragma unroll
        for (int j = 0; j < 4; ++j) {
            float y = (u[t][j] - mean[j]) * rstd[j] * gv[t] + ev[t];
            hp[(q * 4 + j) * HPAD + t * 16 + n16] = (__bf16)y;
        }
}

__global__ __launch_bounds__(512, 4)
void edge_model_kernel(const float* __restrict__ srcp,
                       const float* __restrict__ dstp,
                       const float* __restrict__ eap,
                       const float* __restrict__ W1, const float* __restrict__ b1,
                       const float* __restrict__ g1, const float* __restrict__ be1,
                       const float* __restrict__ W2, const float* __restrict__ b2,
                       const float* __restrict__ g2, const float* __restrict__ be2,
                       const float* __restrict__ W3, const float* __restrict__ b3,
                       float* __restrict__ out, int E) {
    // Weight fragments, fragment-contiguous: fragment fid, lane l -> wlds[fid*512 + l*8 .. +8)
    __shared__ alignas(16) __bf16 wlds[NFRAG * 64 * 8];        // 36,864 B
    // Two per-wave h tiles (tileA, tileB). Each tile's buffer is reused for
    // h1 then h2 (sequentially live; validated in R5). Total LDS 71,680 B ->
    // 2 blocks/CU, 16 waves/CU — matched to the VGPR<=128 (4 waves/SIMD) cap.
    __shared__ alignas(16) __bf16 hs[NW][2][16 * HPAD];        // 34,816 B

    const int tid = threadIdx.x;
    const int w   = tid >> 6;
    const int l   = tid & 63;
    const int n16 = l & 15;
    const int q   = l >> 4;

    // ---- cooperative fill of weight fragments (once per block) ----
    for (int idx = tid; idx < NFRAG * 64; idx += blockDim.x) {
        int fid = idx >> 6, fl = idx & 63;
        int lq = fl >> 4, ln = fl & 15;
        const float* Wsrc; int ldw, row0, col;
        if (fid < 12)      { int s = fid >> 2,        t = fid & 3;        Wsrc = W1; ldw = 64; row0 = s * 32 + lq * 8; col = t * 16 + ln; }
        else if (fid < 32) { int f = fid - 12, s = f >> 2, t = f & 3;     Wsrc = W2; ldw = 64; row0 = s * 32 + lq * 8; col = t * 16 + ln; }
        else               { int f = fid - 32, s = f >> 1, t = f & 1;     Wsrc = W3; ldw = 32; row0 = s * 32 + lq * 8; col = t * 16 + ln; }
        __bf16* dst = wlds + idx * 8;
#pragma unroll
        for (int jj = 0; jj < 8; ++jj)
            dst[jj] = (__bf16)Wsrc[(row0 + jj) * ldw + col];
    }

    // per-lane affine params (channel c = t*16 + n16 in C-layout)
    float b1v[4], g1v[4], e1v[4], b2v[4], g2v[4], e2v[4], b3v[2];
#pragma unroll
    for (int t = 0; t < 4; ++t) {
        int c = t * 16 + n16;
        b1v[t] = b1[c]; g1v[t] = g1[c]; e1v[t] = be1[c];
        b2v[t] = b2[c]; g2v[t] = g2[c]; e2v[t] = be2[c];
    }
    b3v[0] = b3[n16];
    b3v[1] = b3[16 + n16];

    __syncthreads();   // weights visible to all waves; no block barriers after this

    // Supertile = 32 rows = tileA (rows e0..e0+15) + tileB (rows e0+16..e0+31).
    const int nSuper = (E + 31) >> 5;
    const int stride = gridDim.x * NW;
    __bf16* hA = &hs[w][0][0];
    __bf16* hB = &hs[w][1][0];
    const __bf16* wl = wlds + l * 8;   // lane-local base; fragment fid at wl + fid*512

    int st = blockIdx.x * NW + w;
    if (st >= nSuper) return;

    // first supertile's x0 fragments (A: rows e0+n16, B: rows e0+16+n16)
    bf16x8 a0A[3], a0B[3];
    {
        const size_t baA = (size_t)min((st << 5) + n16,      E - 1) * 32 + q * 8;
        const size_t baB = (size_t)min((st << 5) + 16 + n16, E - 1) * 32 + q * 8;
        a0A[0] = cvt_frag(((const float4*)(srcp + baA))[0], ((const float4*)(srcp + baA))[1]);
        a0A[1] = cvt_frag(((const float4*)(dstp + baA))[0], ((const float4*)(dstp + baA))[1]);
        a0A[2] = cvt_frag(((const float4*)(eap  + baA))[0], ((const float4*)(eap  + baA))[1]);
        a0B[0] = cvt_frag(((const float4*)(srcp + baB))[0], ((const float4*)(srcp + baB))[1]);
        a0B[1] = cvt_frag(((const float4*)(dstp + baB))[0], ((const float4*)(dstp + baB))[1]);
        a0B[2] = cvt_frag(((const float4*)(eap  + baB))[0], ((const float4*)(eap  + baB))[1]);
    }

    for (;;) {
        const int e0 = st << 5;
        const int ns = st + stride;

        // ---- GEMM1: two [16x96] @ [96x64], weight fragment shared A/B ----
        f32x4 accA1[4] = {}, accB1[4] = {};
#pragma unroll
        for (int s = 0; s < 3; ++s)
#pragma unroll
            for (int t = 0; t < 4; ++t) {
                bf16x8 wf = *(const bf16x8*)(wl + (s * 4 + t) * 512);
                accA1[t] = __builtin_amdgcn_mfma_f32_16x16x32_bf16(a0A[s], wf, accA1[t], 0, 0, 0);
                accB1[t] = __builtin_amdgcn_mfma_f32_16x16x32_bf16(a0B[s], wf, accB1[t], 0, 0, 0);
            }

        ln_epilogue(accA1, b1v, g1v, e1v, hA, n16, q);
        ln_epilogue(accB1, b1v, g1v, e1v, hB, n16, q);
        LDS_WAIT();

        // ---- GEMM2: two [16x160] @ [160x64], A-operand = [h1 | x0] ----
        f32x4 accA2[4] = {}, accB2[4] = {};
        bf16x8 hA0 = ld_frag_lds8(hA + n16 * HPAD + q * 8);
        bf16x8 hA1 = ld_frag_lds8(hA + n16 * HPAD + 32 + q * 8);
        bf16x8 hB0 = ld_frag_lds8(hB + n16 * HPAD + q * 8);
        bf16x8 hB1 = ld_frag_lds8(hB + n16 * HPAD + 32 + q * 8);
#pragma unroll
        for (int t = 0; t < 4; ++t) {
            bf16x8 wf = *(const bf16x8*)(wl + (12 + t) * 512);
            accA2[t] = __builtin_amdgcn_mfma_f32_16x16x32_bf16(hA0, wf, accA2[t], 0, 0, 0);
            accB2[t] = __builtin_amdgcn_mfma_f32_16x16x32_bf16(hB0, wf, accB2[t], 0, 0, 0);
        }
#pragma unroll
        for (int t = 0; t < 4; ++t) {
            bf16x8 wf = *(const bf16x8*)(wl + (16 + t) * 512);
            accA2[t] = __builtin_amdgcn_mfma_f32_16x16x32_bf16(hA1, wf, accA2[t], 0, 0, 0);
            accB2[t] = __builtin_amdgcn_mfma_f32_16x16x32_bf16(hB1, wf, accB2[t], 0, 0, 0);
        }
#pragma unroll
        for (int s = 0; s < 3; ++s)
#pragma unroll
            for (int t = 0; t < 4; ++t) {
                bf16x8 wf = *(const bf16x8*)(wl + (20 + s * 4 + t) * 512);
                accA2[t] = __builtin_amdgcn_mfma_f32_16x16x32_bf16(a0A[s], wf, accA2[t], 0, 0, 0);
                accB2[t] = __builtin_amdgcn_mfma_f32_16x16x32_bf16(a0B[s], wf, accB2[t], 0, 0, 0);
            }

        // h2 overwrites h1 per tile (h1 fully consumed; same-wave DS in-order).
        ln_epilogue(accA2, b2v, g2v, e2v, hA, n16, q);
        ln_epilogue(accB2, b2v, g2v, e2v, hB, n16, q);
        LDS_WAIT();

        // ---- prefetch next supertile's x0 HERE (a0/acc1 dead -> VGPR peak stays <128;
        //      distance covers GEMM3 + 16 stores + loop latch) ----
        const int pt = (ns < nSuper) ? ns : st;
        const size_t pbA = (size_t)min((pt << 5) + n16,      E - 1) * 32 + q * 8;
        const size_t pbB = (size_t)min((pt << 5) + 16 + n16, E - 1) * 32 + q * 8;
        float4 pA0a = ((const float4*)(srcp + pbA))[0], pA0b = ((const float4*)(srcp + pbA))[1];
        float4 pA1a = ((const float4*)(dstp + pbA))[0], pA1b = ((const float4*)(dstp + pbA))[1];
        float4 pA2a = ((const float4*)(eap  + pbA))[0], pA2b = ((const float4*)(eap  + pbA))[1];
        float4 pB0a = ((const float4*)(srcp + pbB))[0], pB0b = ((const float4*)(srcp + pbB))[1];
        float4 pB1a = ((const float4*)(dstp + pbB))[0], pB1b = ((const float4*)(dstp + pbB))[1];
        float4 pB2a = ((const float4*)(eap  + pbB))[0], pB2b = ((const float4*)(eap  + pbB))[1];

        // ---- GEMM3: two [16x64] @ [64x32] + b3 ----
        f32x4 accA3[2] = {}, accB3[2] = {};
#pragma unroll
        for (int s = 0; s < 2; ++s) {
            bf16x8 hfA = ld_frag_lds8(hA + n16 * HPAD + s * 32 + q * 8);
            bf16x8 hfB = ld_frag_lds8(hB + n16 * HPAD + s * 32 + q * 8);
#pragma unroll
            for (int t = 0; t < 2; ++t) {
                bf16x8 wf = *(const bf16x8*)(wl + (32 + s * 2 + t) * 512);
                accA3[t] = __builtin_amdgcn_mfma_f32_16x16x32_bf16(hfA, wf, accA3[t], 0, 0, 0);
                accB3[t] = __builtin_amdgcn_mfma_f32_16x16x32_bf16(hfB, wf, accB3[t], 0, 0, 0);
            }
        }

        // store: lane holds out[e0 (+16) + 4q + j][t*16 + n16]
#pragma unroll
        for (int t = 0; t < 2; ++t)
#pragma unroll
            for (int j = 0; j < 4; ++j) {
                int rA = e0 + q * 4 + j;
                int rB = e0 + 16 + q * 4 + j;
                if (rA < E) out[(size_t)rA * 32 + t * 16 + n16] = accA3[t][j] + b3v[t];
                if (rB < E) out[(size_t)rB * 32 + t * 16 + n16] = accB3[t][j] + b3v[t];
            }

        if (ns >= nSuper) break;
        st = ns;
        a0A[0] = cvt_frag(pA0a, pA0b);
        a0A[1] = cvt_frag(pA1a, pA1b);
        a0A[2] = cvt_frag(pA2a, pA2b);
        a0B[0] = cvt_frag(pB0a, pB0b);
        a0B[1] = cvt_frag(pB1a, pB1b);
        a0B[2] = cvt_frag(pB2a, pB2b);
    }
}

extern "C" void kernel_launch(void* const* d_in, const int* in_sizes, int n_in,
                              void* d_out, int out_size, void* d_ws, size_t ws_size,
                              hipStream_t stream) {
    (void)n_in; (void)out_size; (void)d_ws; (void)ws_size;
    const float* srcp = (const float*)d_in[0];
    const float* dstp = (const float*)d_in[1];
    const float* eap  = (const float*)d_in[2];
    const float* W1   = (const float*)d_in[3];
    const float* b1   = (const float*)d_in[4];
    const float* g1   = (const float*)d_in[5];
    const float* be1  = (const float*)d_in[6];
    const float* W2   = (const float*)d_in[7];
    const float* b2   = (const float*)d_in[8];
    const float* g2   = (const float*)d_in[9];
    const float* be2  = (const float*)d_in[10];
    const float* W3   = (const float*)d_in[11];
    const float* b3   = (const float*)d_in[12];
    float* out = (float*)d_out;

    const int E = in_sizes[0] / 32;
    const int nSuper = (E + 31) / 32;
    int blocks = (nSuper + NW - 1) / NW;
    if (blocks > 512) blocks = 512;  // 2 blocks/CU (LDS = 71,680 B), 16 waves/CU

    edge_model_kernel<<<blocks, 512, 0, stream>>>(srcp, dstp, eap, W1, b1, g1, be1,
                                                  W2, b2, g2, be2, W3, b3, out, E);
}

// Round 7
// 412.064 us; speedup vs baseline: 1.1077x; 1.1077x over previous
//
#include <hip/hip_runtime.h>

typedef __bf16 bf16x8 __attribute__((ext_vector_type(8)));
typedef __bf16 bf16x4 __attribute__((ext_vector_type(4)));
typedef float  f32x4  __attribute__((ext_vector_type(4)));

#define NW 8       // waves per block (512 threads)
#define HPAD 68    // bf16 elems per LDS h-row (136 B); measured 0 bank conflicts
#define NFRAG 36   // 12 (W1) + 20 (W2) + 4 (W3) fragment tiles
#define LDS_WAIT() asm volatile("s_waitcnt lgkmcnt(0)" ::: "memory")

static __device__ __forceinline__ bf16x8 ld_frag_lds8(const __bf16* p) {
    bf16x4 lo = *(const bf16x4*)p;
    bf16x4 hi = *(const bf16x4*)(p + 4);
    bf16x8 r;
    r[0] = lo[0]; r[1] = lo[1]; r[2] = lo[2]; r[3] = lo[3];
    r[4] = hi[0]; r[5] = hi[1]; r[6] = hi[2]; r[7] = hi[3];
    return r;
}

static __device__ __forceinline__ bf16x8 cvt_frag(float4 v0, float4 v1) {
    bf16x8 r;
    r[0] = (__bf16)v0.x; r[1] = (__bf16)v0.y; r[2] = (__bf16)v0.z; r[3] = (__bf16)v0.w;
    r[4] = (__bf16)v1.x; r[5] = (__bf16)v1.y; r[6] = (__bf16)v1.z; r[7] = (__bf16)v1.w;
    return r;
}

// x + dpp_move(x): VALU-pipe cross-lane add (replaces ds_bpermute-based __shfl_xor).
// ctrl: 0xB1 = quad_perm [1,0,3,2] (xor1), 0x4E = quad_perm [2,3,0,1] (xor2),
//       0x124 = row_ror:4, 0x128 = row_ror:8 (rotation rounds are valid for
//       sum-reduction after the two quad rounds; all within a 16-lane row).
template <int CTRL>
static __device__ __forceinline__ float dpp_add(float x) {
    int v = __builtin_amdgcn_update_dpp(0, __float_as_int(x), CTRL, 0xF, 0xF, true);
    return x + __int_as_float(v);
}

// ReLU(acc + b) -> LayerNorm(*g, +be) -> bf16 scatter into per-wave LDS tile (C-layout).
// Reduction over the 16 lanes of each quarter runs on the VALU pipe via DPP —
// zero DS-pipe ops (the LDS pipe is the measured bottleneck, ~67% busy in R5).
static __device__ __forceinline__ void ln_epilogue(const f32x4* acc, const float* bv,
                                                   const float* gv, const float* ev,
                                                   __bf16* hp, int n16, int q) {
    float u[4][4];
    float sm[4] = {0.f, 0.f, 0.f, 0.f};
    float sq[4] = {0.f, 0.f, 0.f, 0.f};
#pragma unroll
    for (int t = 0; t < 4; ++t)
#pragma unroll
        for (int j = 0; j < 4; ++j) {
            float x = acc[t][j] + bv[t];
            x = fmaxf(x, 0.0f);
            u[t][j] = x;
            sm[j] += x;
            sq[j] += x * x;
        }
#pragma unroll
    for (int j = 0; j < 4; ++j) {
        sm[j] = dpp_add<0xB1>(sm[j]);   sq[j] = dpp_add<0xB1>(sq[j]);   // xor1
        sm[j] = dpp_add<0x4E>(sm[j]);   sq[j] = dpp_add<0x4E>(sq[j]);   // xor2
        sm[j] = dpp_add<0x124>(sm[j]);  sq[j] = dpp_add<0x124>(sq[j]);  // ror4
        sm[j] = dpp_add<0x128>(sm[j]);  sq[j] = dpp_add<0x128>(sq[j]);  // ror8
    }
    float mean[4], rstd[4];
#pragma unroll
    for (int j = 0; j < 4; ++j) {
        mean[j] = sm[j] * 0.015625f;
        float v = sq[j] * 0.015625f - mean[j] * mean[j];
        rstd[j] = rsqrtf(fmaxf(v, 0.0f) + 1e-5f);
    }
#pragma unroll
    for (int t = 0; t < 4; ++t)
#pragma unroll
        for (int j = 0; j < 4; ++j) {
            float y = (u[t][j] - mean[j]) * rstd[j] * gv[t] + ev[t];
            hp[(q * 4 + j) * HPAD + t * 16 + n16] = (__bf16)y;
        }
}

__global__ __launch_bounds__(512, 4)
void edge_model_kernel(const float* __restrict__ srcp,
                       const float* __restrict__ dstp,
                       const float* __restrict__ eap,
                       const float* __restrict__ W1, const float* __restrict__ b1,
                       const float* __restrict__ g1, const float* __restrict__ be1,
                       const float* __restrict__ W2, const float* __restrict__ b2,
                       const float* __restrict__ g2, const float* __restrict__ be2,
                       const float* __restrict__ W3, const float* __restrict__ b3,
                       float* __restrict__ out, int E) {
    // Weight fragments, fragment-contiguous: fragment fid, lane l -> wlds[fid*512 + l*8 .. +8)
    __shared__ alignas(16) __bf16 wlds[NFRAG * 64 * 8];        // 36,864 B
    // Single per-wave h tile, reused for h1 then h2 (sequentially live; same-wave
    // DS ops are in-order; validated correct in R1/R5).
    __shared__ alignas(16) __bf16 hs[NW][16 * HPAD];           // 17,408 B -> total 54,272 B
    // 3 blocks/CU: 3 * 54,272 = 162,816 <= 163,840 (160 KiB). 24 waves/CU.

    const int tid = threadIdx.x;
    const int w   = tid >> 6;
    const int l   = tid & 63;
    const int n16 = l & 15;
    const int q   = l >> 4;

    // ---- cooperative fill of weight fragments (once per block) ----
    for (int idx = tid; idx < NFRAG * 64; idx += blockDim.x) {
        int fid = idx >> 6, fl = idx & 63;
        int lq = fl >> 4, ln = fl & 15;
        const float* Wsrc; int ldw, row0, col;
        if (fid < 12)      { int s = fid >> 2,        t = fid & 3;        Wsrc = W1; ldw = 64; row0 = s * 32 + lq * 8; col = t * 16 + ln; }
        else if (fid < 32) { int f = fid - 12, s = f >> 2, t = f & 3;     Wsrc = W2; ldw = 64; row0 = s * 32 + lq * 8; col = t * 16 + ln; }
        else               { int f = fid - 32, s = f >> 1, t = f & 1;     Wsrc = W3; ldw = 32; row0 = s * 32 + lq * 8; col = t * 16 + ln; }
        __bf16* dst = wlds + idx * 8;
#pragma unroll
        for (int jj = 0; jj < 8; ++jj)
            dst[jj] = (__bf16)Wsrc[(row0 + jj) * ldw + col];
    }

    // per-lane affine params (channel c = t*16 + n16 in C-layout)
    float b1v[4], g1v[4], e1v[4], b2v[4], g2v[4], e2v[4], b3v[2];
#pragma unroll
    for (int t = 0; t < 4; ++t) {
        int c = t * 16 + n16;
        b1v[t] = b1[c]; g1v[t] = g1[c]; e1v[t] = be1[c];
        b2v[t] = b2[c]; g2v[t] = g2[c]; e2v[t] = be2[c];
    }
    b3v[0] = b3[n16];
    b3v[1] = b3[16 + n16];

    __syncthreads();   // weights visible to all waves; no block barriers after this

    const int nTiles = (E + 15) >> 4;
    const int stride = gridDim.x * NW;
    __bf16* hp = &hs[w][0];
    const __bf16* wl = wlds + l * 8;   // lane-local base; fragment fid at wl + fid*512

    int tile = blockIdx.x * NW + w;
    if (tile >= nTiles) return;

    // first tile's x0 fragments
    bf16x8 a0[3];
    {
        const size_t abase = (size_t)min((tile << 4) + n16, E - 1) * 32 + q * 8;
        a0[0] = cvt_frag(((const float4*)(srcp + abase))[0], ((const float4*)(srcp + abase))[1]);
        a0[1] = cvt_frag(((const float4*)(dstp + abase))[0], ((const float4*)(dstp + abase))[1]);
        a0[2] = cvt_frag(((const float4*)(eap  + abase))[0], ((const float4*)(eap  + abase))[1]);
    }

    for (;;) {
        const int e0 = tile << 4;
        const int nt = tile + stride;

        // ---- prefetch next tile's x0 (consumed at loop end) ----
        const int pt = (nt < nTiles) ? nt : tile;
        const size_t pbase = (size_t)min((pt << 4) + n16, E - 1) * 32 + q * 8;
        float4 p0a = ((const float4*)(srcp + pbase))[0];
        float4 p0b = ((const float4*)(srcp + pbase))[1];
        float4 p1a = ((const float4*)(dstp + pbase))[0];
        float4 p1b = ((const float4*)(dstp + pbase))[1];
        float4 p2a = ((const float4*)(eap  + pbase))[0];
        float4 p2b = ((const float4*)(eap  + pbase))[1];

        // ---- GEMM1: [16x96] @ [96x64] ----
        f32x4 acc1[4] = {};
#pragma unroll
        for (int s = 0; s < 3; ++s)
#pragma unroll
            for (int t = 0; t < 4; ++t) {
                bf16x8 wf = *(const bf16x8*)(wl + (s * 4 + t) * 512);
                acc1[t] = __builtin_amdgcn_mfma_f32_16x16x32_bf16(a0[s], wf, acc1[t], 0, 0, 0);
            }

        ln_epilogue(acc1, b1v, g1v, e1v, hp, n16, q);
        // NOTE: no blocking wait here. The x0-part of GEMM2 below is independent
        // of h1; its 12 MFMAs + wf reads run while the 16 h1 ds_writes drain
        // (same-wave DS ops retire in order).

        // ---- GEMM2: [16x160] @ [160x64], A = [h1 | x0]; x0-part FIRST ----
        f32x4 acc2[4] = {};
#pragma unroll
        for (int s = 0; s < 3; ++s)
#pragma unroll
            for (int t = 0; t < 4; ++t) {
                bf16x8 wf = *(const bf16x8*)(wl + (20 + s * 4 + t) * 512);
                acc2[t] = __builtin_amdgcn_mfma_f32_16x16x32_bf16(a0[s], wf, acc2[t], 0, 0, 0);
            }

        LDS_WAIT();   // h1 writes (issued long ago) certainly drained; order reads after
        bf16x8 h1f0 = ld_frag_lds8(hp + n16 * HPAD + q * 8);
        bf16x8 h1f1 = ld_frag_lds8(hp + n16 * HPAD + 32 + q * 8);
#pragma unroll
        for (int t = 0; t < 4; ++t) {
            bf16x8 wf = *(const bf16x8*)(wl + (12 + t) * 512);
            acc2[t] = __builtin_amdgcn_mfma_f32_16x16x32_bf16(h1f0, wf, acc2[t], 0, 0, 0);
        }
#pragma unroll
        for (int t = 0; t < 4; ++t) {
            bf16x8 wf = *(const bf16x8*)(wl + (16 + t) * 512);
            acc2[t] = __builtin_amdgcn_mfma_f32_16x16x32_bf16(h1f1, wf, acc2[t], 0, 0, 0);
        }

        // h2 overwrites h1 (h1 fully consumed: the h-part MFMAs above waited on
        // the h1 ds_reads; same-wave DS pipe is in-order).
        ln_epilogue(acc2, b2v, g2v, e2v, hp, n16, q);
        LDS_WAIT();

        // ---- GEMM3: [16x64] @ [64x32] + b3 ----
        f32x4 acc3[2] = {};
#pragma unroll
        for (int s = 0; s < 2; ++s) {
            bf16x8 h2f = ld_frag_lds8(hp + n16 * HPAD + s * 32 + q * 8);
#pragma unroll
            for (int t = 0; t < 2; ++t) {
                bf16x8 wf = *(const bf16x8*)(wl + (32 + s * 2 + t) * 512);
                acc3[t] = __builtin_amdgcn_mfma_f32_16x16x32_bf16(h2f, wf, acc3[t], 0, 0, 0);
            }
        }

        // store: lane holds out[e0 + 4q + j][t*16 + n16]
#pragma unroll
        for (int t = 0; t < 2; ++t)
#pragma unroll
            for (int j = 0; j < 4; ++j) {
                int r = e0 + q * 4 + j;
                if (r < E) out[(size_t)r * 32 + t * 16 + n16] = acc3[t][j] + b3v[t];
            }

        if (nt >= nTiles) break;
        tile = nt;
        a0[0] = cvt_frag(p0a, p0b);
        a0[1] = cvt_frag(p1a, p1b);
        a0[2] = cvt_frag(p2a, p2b);
    }
}

extern "C" void kernel_launch(void* const* d_in, const int* in_sizes, int n_in,
                              void* d_out, int out_size, void* d_ws, size_t ws_size,
                              hipStream_t stream) {
    (void)n_in; (void)out_size; (void)d_ws; (void)ws_size;
    const float* srcp = (const float*)d_in[0];
    const float* dstp = (const float*)d_in[1];
    const float* eap  = (const float*)d_in[2];
    const float* W1   = (const float*)d_in[3];
    const float* b1   = (const float*)d_in[4];
    const float* g1   = (const float*)d_in[5];
    const float* be1  = (const float*)d_in[6];
    const float* W2   = (const float*)d_in[7];
    const float* b2   = (const float*)d_in[8];
    const float* g2   = (const float*)d_in[9];
    const float* be2  = (const float*)d_in[10];
    const float* W3   = (const float*)d_in[11];
    const float* b3   = (const float*)d_in[12];
    float* out = (float*)d_out;

    const int E = in_sizes[0] / 32;
    const int nTiles = (E + 15) / 16;
    int blocks = (nTiles + NW - 1) / NW;
    if (blocks > 768) blocks = 768;  // 3 blocks/CU (LDS = 54,272 B), 24 waves/CU

    edge_model_kernel<<<blocks, 512, 0, stream>>>(srcp, dstp, eap, W1, b1, g1, be1,
                                                  W2, b2, g2, be2, W3, b3, out, E);
}